// Round 6
// baseline (342.046 us; speedup 1.0000x reference)
//
#include <hip/hip_runtime.h>
#include <hip/hip_bf16.h>
#include <math.h>

#define N_NODES 10000
#define D_MODEL 128
#define E_EDGES 320000
#define P_EDGES 80000
#define LN_EPS 1e-5f
#define CAP 32             // slots per bucket (Poisson(8): P(>32) ~ 1e-11)
#define M_ROWS 50000       // = 625 blocks * 80 rows, exact
#define NCOLS 160          // delta(128) + B(16) + C(16)

typedef __attribute__((ext_vector_type(8))) short bf16x8;
typedef __attribute__((ext_vector_type(4))) float f32x4;

__device__ __forceinline__ unsigned short f2bf(float f) {
    __hip_bfloat16 h = __float2bfloat16(f);
    return *reinterpret_cast<unsigned short*>(&h);
}
__device__ __forceinline__ float bf2f(unsigned int u) {
    return __uint_as_float(u << 16);
}

// ---------------------------------------------------------------------------
// prep_all (+csr folded in): pack Wcat(160) + W_out + W_g, x/rel -> bf16
// (x also into s=0 token rows), AND the CSR bucket scatter (reads raw edge
// arrays; cnt is pre-zeroed by hipMemsetAsync -> no in-kernel zeroing race).
// ed4 intermediate eliminated entirely.
// ---------------------------------------------------------------------------
__global__ __launch_bounds__(256) void prep_all(
    const float* __restrict__ Wd, const float* __restrict__ Wb,
    const float* __restrict__ Wc, const float* __restrict__ Wg,
    const float* __restrict__ W_out,
    const float* __restrict__ x, const float* __restrict__ rel,
    const int* __restrict__ edge_index, const int* __restrict__ edge_type,
    const int* __restrict__ perms,
    unsigned short* __restrict__ Bp, unsigned short* __restrict__ Wop,
    unsigned short* __restrict__ Wgp,
    unsigned short* __restrict__ x_bf, unsigned short* __restrict__ rel_bf,
    int* __restrict__ cnt, int2* __restrict__ slots,
    unsigned short* __restrict__ tokens)
{
    int gid = blockIdx.x * 256 + threadIdx.x;
    if (gid < 20480) {                         // Bp: 128 x 160
        int k = gid / NCOLS, n = gid - (gid / NCOLS) * NCOLS;
        float v;
        if (n < 128)      v = Wd[k * 128 + n];
        else if (n < 144) v = Wb[k * 16 + (n - 128)];
        else              v = Wc[k * 16 + (n - 144)];
        Bp[((size_t)(k >> 3) * NCOLS + n) * 8 + (k & 7)] = f2bf(v);
    } else if (gid < 36864) {                  // Wop: 128 x 128
        int i = gid - 20480;
        int k = i >> 7, n = i & 127;
        Wop[((size_t)(k >> 3) * 128 + n) * 8 + (k & 7)] = f2bf(W_out[k * 128 + n]);
    } else if (gid < 53248) {                  // Wgp: 128 x 128
        int i = gid - 36864;
        int k = i >> 7, n = i & 127;
        Wgp[((size_t)(k >> 3) * 128 + n) * 8 + (k & 7)] = f2bf(Wg[k * 128 + n]);
    } else if (gid < 78848) {                  // rel_bf
        int i = gid - 53248;
        rel_bf[i] = f2bf(rel[i]);
    } else if (gid < 1358848) {                // x -> bf16 + s=0 token rows
        int i = gid - 78848;
        unsigned short v = f2bf(x[i]);
        x_bf[i] = v;
        tokens[(size_t)(i >> 7) * 640 + (i & 127)] = v;
    } else if (gid < 1678848) {                // CSR scatter (cnt pre-zeroed)
        int i = gid - 1358848;
        int s = i / P_EDGES;
        int e = perms[i];
        int src = edge_index[e];
        int dst = edge_index[E_EDGES + e];
        int ty  = edge_type[e];
        int b = dst * 4 + s;
        int pos = atomicAdd(&cnt[b], 1);
        if (pos < CAP) slots[(size_t)b * CAP + pos] = make_int2(src, ty);
    }
}

// ---------------------------------------------------------------------------
// Gather (wide: 10000 blocks): one wave per bucket; lane = 2 dims;
// 4 edges in flight.
// ---------------------------------------------------------------------------
__global__ __launch_bounds__(256) void gather_tokens(
    const unsigned short* __restrict__ x_bf,
    const int* __restrict__ cnt, const int2* __restrict__ slots,
    const unsigned short* __restrict__ rel_bf,
    unsigned short* __restrict__ tokens)
{
    int n = blockIdx.x;
    int w = threadIdx.x >> 6, lane = threadIdx.x & 63;
    int b = n * 4 + w;
    int c = cnt[b];
    int cc = c < CAP ? c : CAP;
    const int2* sl = slots + (size_t)b * CAP;
    const unsigned int* xu = (const unsigned int*)x_bf;
    const unsigned int* ru = (const unsigned int*)rel_bf;
    float ax = 0.f, ay = 0.f;
    int j = 0;
    for (; j + 4 <= cc; j += 4) {
        int4 e01 = *(const int4*)(sl + j);
        int4 e23 = *(const int4*)(sl + j + 2);
        unsigned int x0 = xu[(size_t)e01.x * 64 + lane];
        unsigned int r0 = ru[(size_t)e01.y * 64 + lane];
        unsigned int x1 = xu[(size_t)e01.z * 64 + lane];
        unsigned int r1 = ru[(size_t)e01.w * 64 + lane];
        unsigned int x2 = xu[(size_t)e23.x * 64 + lane];
        unsigned int r2 = ru[(size_t)e23.y * 64 + lane];
        unsigned int x3 = xu[(size_t)e23.z * 64 + lane];
        unsigned int r3 = ru[(size_t)e23.w * 64 + lane];
        ax += (bf2f(x0 & 0xffffu) + bf2f(r0 & 0xffffu))
            + (bf2f(x1 & 0xffffu) + bf2f(r1 & 0xffffu))
            + (bf2f(x2 & 0xffffu) + bf2f(r2 & 0xffffu))
            + (bf2f(x3 & 0xffffu) + bf2f(r3 & 0xffffu));
        ay += (bf2f(x0 >> 16) + bf2f(r0 >> 16))
            + (bf2f(x1 >> 16) + bf2f(r1 >> 16))
            + (bf2f(x2 >> 16) + bf2f(r2 >> 16))
            + (bf2f(x3 >> 16) + bf2f(r3 >> 16));
    }
    if (j + 2 <= cc) {
        int4 e01 = *(const int4*)(sl + j);
        unsigned int x0 = xu[(size_t)e01.x * 64 + lane];
        unsigned int r0 = ru[(size_t)e01.y * 64 + lane];
        unsigned int x1 = xu[(size_t)e01.z * 64 + lane];
        unsigned int r1 = ru[(size_t)e01.w * 64 + lane];
        ax += (bf2f(x0 & 0xffffu) + bf2f(r0 & 0xffffu))
            + (bf2f(x1 & 0xffffu) + bf2f(r1 & 0xffffu));
        ay += (bf2f(x0 >> 16) + bf2f(r0 >> 16))
            + (bf2f(x1 >> 16) + bf2f(r1 >> 16));
        j += 2;
    }
    if (j < cc) {
        int2 se = sl[j];
        unsigned int xa = xu[(size_t)se.x * 64 + lane];
        unsigned int ra = ru[(size_t)se.y * 64 + lane];
        ax += bf2f(xa & 0xffffu) + bf2f(ra & 0xffffu);
        ay += bf2f(xa >> 16) + bf2f(ra >> 16);
    }
    float inv = 1.f / fmaxf((float)c, 1.f);
    unsigned int pack = (unsigned int)f2bf(ax * inv)
                      | ((unsigned int)f2bf(ay * inv) << 16);
    ((unsigned int*)tokens)[((size_t)n * 5 + w + 1) * 64 + lane] = pack;
}

// ---------------------------------------------------------------------------
// MEGA: gemm1 + scan + out fused per 16-node block (80 token rows).
// NOW 512 threads (8 waves): kernel is latency-bound (R5: dur tracked
// inversely with occupancy), so double the waves per block.
// __launch_bounds__(512,4): VGPR cap 128 (need ~100 -> no spill),
// 2 blocks/CU resident.
// ---------------------------------------------------------------------------
__global__ __launch_bounds__(512, 4) void mega(
    const unsigned short* __restrict__ tokens,
    const unsigned short* __restrict__ Bp,
    const unsigned short* __restrict__ Wop,
    const unsigned short* __restrict__ Wgp,
    const unsigned short* __restrict__ x_bf,
    const float* __restrict__ x,
    const float* __restrict__ log_A,
    const float* __restrict__ b_delta, const float* __restrict__ b_g,
    const float* __restrict__ b_out,
    const float* __restrict__ ln_g, const float* __restrict__ ln_b,
    float* __restrict__ out)
{
    const int tid = threadIdx.x;
    const int wv = tid >> 6, lane = tid & 63;
    const int quad = lane >> 4, l16 = lane & 15;
    const int m0 = blockIdx.x * 80;       // global token-row base
    const int n0 = blockIdx.x * 16;       // global node base

    // LDS: phase1 {delta 20480 | bcf 10240 | so 4096}, out-phase aliases
    // res/pmu/pv2/mu into the (then-dead) delta/bcf regions.
    __shared__ __align__(16) char smem[34816];
    unsigned short* s_delta = (unsigned short*)smem;            // [80][128] bf16
    float*          s_bcf   = (float*)(smem + 20480);           // [80][32] f32
    unsigned short* s_so    = (unsigned short*)(smem + 30720);  // [16][128] bf16 (swz)
    float* s_res  = (float*)smem;                               // [16][132] f32
    float* s_pmu  = (float*)(smem + 20480);                     // [16][16]
    float* s_pv2  = (float*)(smem + 21504);                     // [16][16]
    float* s_mu   = (float*)(smem + 22528);                     // [16]
    float* s_rstd = (float*)(smem + 22592);                     // [16]

    // ---------------- phase 1: GEMM1  Z[80,160] -> s_delta | s_bcf
    // 50 units = 5 row-frags x 10 col-tiles, round-robin over 8 waves.
    for (int u = wv; u < 50; u += 8) {
        int f = u / 10, t = u - (u / 10) * 10;
        f32x4 acc = {0.f, 0.f, 0.f, 0.f};
        const unsigned short* arow =
            tokens + (size_t)(m0 + f * 16 + l16) * 128 + quad * 8;
        #pragma unroll
        for (int kc = 0; kc < 128; kc += 32) {
            bf16x8 a = *(const bf16x8*)(arow + kc);
            bf16x8 b = *(const bf16x8*)(Bp +
                ((size_t)(kc / 8 + quad) * NCOLS + 16 * t + l16) * 8);
            acc = __builtin_amdgcn_mfma_f32_16x16x32_bf16(a, b, acc, 0, 0, 0);
        }
        int rbase = f * 16 + quad * 4;
        int c = 16 * t + l16;
        #pragma unroll
        for (int reg = 0; reg < 4; ++reg) {
            int r = rbase + reg;              // local row 0..79 (= node*5+s)
            float v = acc[reg];
            if (t < 8) {
                float z = v + b_delta[c];
                float d = (z > 15.f) ? z : log1pf(__expf(z));
                s_delta[r * 128 + c] = f2bf(d);
            } else {
                s_bcf[r * 32 + (c - 128)] = v;   // f32 (B:0-15 | C:16-31)
            }
        }
    }
    __syncthreads();

    // ---------------- phase 2: bidirectional selective scan -> s_so
    // 2048 (node,dim) units / 512 threads = 4 each; thread owns one dim.
    {
        const int dim = tid & 127;
        float Ac[16];
        {
            const float4* la = (const float4*)(log_A + dim * 16);
            #pragma unroll
            for (int q = 0; q < 4; ++q) {
                float4 lv = la[q];
                Ac[q * 4 + 0] = -__expf(lv.x);
                Ac[q * 4 + 1] = -__expf(lv.y);
                Ac[q * 4 + 2] = -__expf(lv.z);
                Ac[q * 4 + 3] = -__expf(lv.w);
            }
        }
        #pragma unroll 1          // keep phase-2 body I-cache-resident
        for (int i = 0; i < 4; ++i) {
            int node = (tid >> 7) + 4 * i;    // local node 0..15
            const float* bcn = s_bcf + node * 160;       // [5][32]
            float tv[5], dl[5];
            {
                const unsigned short* tb =
                    tokens + ((size_t)(n0 + node) * 5) * 128 + dim;
                const unsigned short* db = s_delta + node * 640 + dim;
                #pragma unroll
                for (int s = 0; s < 5; ++s) {
                    tv[s] = bf2f(tb[s * 128]);
                    dl[s] = bf2f(db[s * 128]);
                }
            }
            float st[16], V[16];
            #pragma unroll
            for (int k = 0; k < 16; ++k) { st[k] = 0.f; V[k] = bcn[16 + k]; }
            float total = 0.f;
            #pragma unroll
            for (int s = 0; s < 5; ++s) {
                float dtv = dl[s] * tv[s];
                float yf = 0.f, ub = 0.f;
                #pragma unroll
                for (int k = 0; k < 16; ++k) {
                    float B = bcn[s * 32 + k];
                    float C = bcn[s * 32 + 16 + k];
                    float A = __expf(dl[s] * Ac[k]);
                    st[k] = fmaf(A, st[k], dtv * B);
                    yf = fmaf(st[k], C, yf);
                    ub = fmaf(V[k], B, ub);              // V_s (pre-update)
                    if (s < 4) V[k] = fmaf(A, V[k], bcn[(s + 1) * 32 + 16 + k]);
                }
                total += yf + dtv * ub;
            }
            // swizzled store: chunk(16B) ^= node&7 -> conflict-free b128 reads
            s_so[node * 128 + (((dim >> 3) ^ (node & 7)) << 3) + (dim & 7)] =
                f2bf(total * 0.2f);
        }
    }
    __syncthreads();

    // ---------------- phase 3: out = LN(x + silu(x@Wg+bg)*(so@Wo+bo))
    // 8 waves: wave wv owns col-tile [16wv, 16wv+16).
    {
        f32x4 accO = {0,0,0,0};
        f32x4 accG = {0,0,0,0};
        const unsigned short* grow = x_bf + (size_t)(n0 + l16) * 128 + quad * 8;
        #pragma unroll
        for (int kc = 0; kc < 128; kc += 32) {
            // so A-frag from LDS with matching swizzle (row=l16, chunk=kc/8+quad)
            bf16x8 a = *(const bf16x8*)(s_so + l16 * 128 +
                           (((kc / 8 + quad) ^ (l16 & 7)) << 3));
            bf16x8 ag = *(const bf16x8*)(grow + kc);
            size_t bi = ((size_t)(kc / 8 + quad) * 128 + 16 * wv + l16) * 8;
            bf16x8 bo = *(const bf16x8*)(Wop + bi);
            bf16x8 bg = *(const bf16x8*)(Wgp + bi);
            accO = __builtin_amdgcn_mfma_f32_16x16x32_bf16(a,  bo, accO, 0, 0, 0);
            accG = __builtin_amdgcn_mfma_f32_16x16x32_bf16(ag, bg, accG, 0, 0, 0);
        }

        {
            int c = wv * 16 + l16;
            #pragma unroll
            for (int reg = 0; reg < 4; ++reg) {
                int lrow = quad * 4 + reg;
                float o  = accO[reg] + b_out[c];
                float gl = accG[reg] + b_g[c];
                float gate = gl / (1.f + __expf(-gl));
                s_res[lrow * 132 + c] = x[(size_t)(n0 + lrow) * 128 + c] + gate * o;
            }
        }
        __syncthreads();

        if (tid < 256) {
            int row = tid >> 4, q = tid & 15;
            float s = 0.f, s2 = 0.f;
            #pragma unroll
            for (int i = 0; i < 8; ++i) {
                float vv = s_res[row * 132 + q + 16 * i];
                s += vv; s2 += vv * vv;
            }
            s_pmu[row * 16 + q] = s; s_pv2[row * 16 + q] = s2;
        }
        __syncthreads();
        if (tid < 16) {
            float s = 0.f, s2 = 0.f;
            #pragma unroll
            for (int i = 0; i < 16; ++i) { s += s_pmu[tid * 16 + i]; s2 += s_pv2[tid * 16 + i]; }
            float mu = s * (1.f / 128.f);
            float var = s2 * (1.f / 128.f) - mu * mu;
            s_mu[tid] = mu;
            s_rstd[tid] = rsqrtf(var + LN_EPS);
        }
        __syncthreads();
        #pragma unroll
        for (int i = 0; i < 4; ++i) {
            int idx = i * 512 + tid;
            int row = idx >> 7, c = idx & 127;
            out[(size_t)(n0 + row) * 128 + c] =
                (s_res[row * 132 + c] - s_mu[row]) * s_rstd[row] * ln_g[c] + ln_b[c];
        }
    }
}

// ---------------------------------------------------------------------------
extern "C" void kernel_launch(void* const* d_in, const int* in_sizes, int n_in,
                              void* d_out, int out_size, void* d_ws, size_t ws_size,
                              hipStream_t stream) {
    const float* x          = (const float*)d_in[0];
    const int*   edge_index = (const int*)  d_in[1];
    const int*   edge_type  = (const int*)  d_in[2];
    const int*   perms      = (const int*)  d_in[3];
    const float* rel_table  = (const float*)d_in[4];
    const float* log_A      = (const float*)d_in[5];
    const float* W_B        = (const float*)d_in[6];
    const float* W_C        = (const float*)d_in[7];
    const float* W_delta    = (const float*)d_in[8];
    const float* b_delta    = (const float*)d_in[9];
    const float* W_g        = (const float*)d_in[10];
    const float* b_g        = (const float*)d_in[11];
    const float* W_out      = (const float*)d_in[12];
    const float* b_out      = (const float*)d_in[13];
    const float* ln_g       = (const float*)d_in[14];
    const float* ln_b       = (const float*)d_in[15];

    char* ws = (char*)d_ws;
    int*            cnt    = (int*)           (ws + 0);          //   163840
    unsigned short* Bp     = (unsigned short*)(ws + 163840);     //    40960
    unsigned short* Wop    = (unsigned short*)(ws + 204800);     //    32768
    unsigned short* Wgp    = (unsigned short*)(ws + 237568);     //    32768
    unsigned short* x_bf   = (unsigned short*)(ws + 270336);     //  2560000
    unsigned short* rel_bf = (unsigned short*)(ws + 2830336);    //    51200
    unsigned short* tokens = (unsigned short*)(ws + 2881536);    // 12800000
    int2*           slots  = (int2*)          (ws + 15681536);   // 10485760

    (void)hipMemsetAsync(cnt, 0, 163840, stream);   // cnt pre-zero (csr atomics)

    prep_all<<<6558, 256, 0, stream>>>(
        W_delta, W_B, W_C, W_g, W_out, x, rel_table, edge_index, edge_type,
        perms, Bp, Wop, Wgp, x_bf, rel_bf, cnt, slots, tokens);

    gather_tokens<<<N_NODES, 256, 0, stream>>>(
        x_bf, cnt, slots, rel_bf, tokens);

    mega<<<N_NODES / 16, 512, 0, stream>>>(
        tokens, Bp, Wop, Wgp, x_bf, x, log_A, b_delta, b_g, b_out,
        ln_g, ln_b, (float*)d_out);
}

// Round 7
// 196.760 us; speedup vs baseline: 1.7384x; 1.7384x over previous
//
#include <hip/hip_runtime.h>
#include <hip/hip_bf16.h>
#include <math.h>

#define N_NODES 10000
#define D_MODEL 128
#define E_EDGES 320000
#define P_EDGES 80000
#define LN_EPS 1e-5f
#define CAP 32             // slots per bucket (Poisson(8): P(>32) ~ 1e-11)
#define M_ROWS 50000       // = 625 blocks * 80 rows, exact
#define NCOLS 160          // delta(128) + B(16) + C(16)

typedef __attribute__((ext_vector_type(8))) short bf16x8;
typedef __attribute__((ext_vector_type(4))) float f32x4;

__device__ __forceinline__ unsigned short f2bf(float f) {
    __hip_bfloat16 h = __float2bfloat16(f);
    return *reinterpret_cast<unsigned short*>(&h);
}
__device__ __forceinline__ float bf2f(unsigned int u) {
    return __uint_as_float(u << 16);
}

// ---------------------------------------------------------------------------
// prep_all (+csr folded in): pack Wcat(160) + W_out + W_g, x/rel -> bf16
// (x also into s=0 token rows), AND the CSR bucket scatter (cnt pre-zeroed
// by hipMemsetAsync).
// ---------------------------------------------------------------------------
__global__ __launch_bounds__(256) void prep_all(
    const float* __restrict__ Wd, const float* __restrict__ Wb,
    const float* __restrict__ Wc, const float* __restrict__ Wg,
    const float* __restrict__ W_out,
    const float* __restrict__ x, const float* __restrict__ rel,
    const int* __restrict__ edge_index, const int* __restrict__ edge_type,
    const int* __restrict__ perms,
    unsigned short* __restrict__ Bp, unsigned short* __restrict__ Wop,
    unsigned short* __restrict__ Wgp,
    unsigned short* __restrict__ x_bf, unsigned short* __restrict__ rel_bf,
    int* __restrict__ cnt, int2* __restrict__ slots,
    unsigned short* __restrict__ tokens)
{
    int gid = blockIdx.x * 256 + threadIdx.x;
    if (gid < 20480) {                         // Bp: 128 x 160
        int k = gid / NCOLS, n = gid - (gid / NCOLS) * NCOLS;
        float v;
        if (n < 128)      v = Wd[k * 128 + n];
        else if (n < 144) v = Wb[k * 16 + (n - 128)];
        else              v = Wc[k * 16 + (n - 144)];
        Bp[((size_t)(k >> 3) * NCOLS + n) * 8 + (k & 7)] = f2bf(v);
    } else if (gid < 36864) {                  // Wop: 128 x 128
        int i = gid - 20480;
        int k = i >> 7, n = i & 127;
        Wop[((size_t)(k >> 3) * 128 + n) * 8 + (k & 7)] = f2bf(W_out[k * 128 + n]);
    } else if (gid < 53248) {                  // Wgp: 128 x 128
        int i = gid - 36864;
        int k = i >> 7, n = i & 127;
        Wgp[((size_t)(k >> 3) * 128 + n) * 8 + (k & 7)] = f2bf(Wg[k * 128 + n]);
    } else if (gid < 78848) {                  // rel_bf
        int i = gid - 53248;
        rel_bf[i] = f2bf(rel[i]);
    } else if (gid < 1358848) {                // x -> bf16 + s=0 token rows
        int i = gid - 78848;
        unsigned short v = f2bf(x[i]);
        x_bf[i] = v;
        tokens[(size_t)(i >> 7) * 640 + (i & 127)] = v;
    } else if (gid < 1678848) {                // CSR scatter (cnt pre-zeroed)
        int i = gid - 1358848;
        int s = i / P_EDGES;
        int e = perms[i];
        int src = edge_index[e];
        int dst = edge_index[E_EDGES + e];
        int ty  = edge_type[e];
        int b = dst * 4 + s;
        int pos = atomicAdd(&cnt[b], 1);
        if (pos < CAP) slots[(size_t)b * CAP + pos] = make_int2(src, ty);
    }
}

// ---------------------------------------------------------------------------
// Gather (wide: 10000 blocks): one wave per bucket; lane = 2 dims;
// 4 edges in flight.
// ---------------------------------------------------------------------------
__global__ __launch_bounds__(256) void gather_tokens(
    const unsigned short* __restrict__ x_bf,
    const int* __restrict__ cnt, const int2* __restrict__ slots,
    const unsigned short* __restrict__ rel_bf,
    unsigned short* __restrict__ tokens)
{
    int n = blockIdx.x;
    int w = threadIdx.x >> 6, lane = threadIdx.x & 63;
    int b = n * 4 + w;
    int c = cnt[b];
    int cc = c < CAP ? c : CAP;
    const int2* sl = slots + (size_t)b * CAP;
    const unsigned int* xu = (const unsigned int*)x_bf;
    const unsigned int* ru = (const unsigned int*)rel_bf;
    float ax = 0.f, ay = 0.f;
    int j = 0;
    for (; j + 4 <= cc; j += 4) {
        int4 e01 = *(const int4*)(sl + j);
        int4 e23 = *(const int4*)(sl + j + 2);
        unsigned int x0 = xu[(size_t)e01.x * 64 + lane];
        unsigned int r0 = ru[(size_t)e01.y * 64 + lane];
        unsigned int x1 = xu[(size_t)e01.z * 64 + lane];
        unsigned int r1 = ru[(size_t)e01.w * 64 + lane];
        unsigned int x2 = xu[(size_t)e23.x * 64 + lane];
        unsigned int r2 = ru[(size_t)e23.y * 64 + lane];
        unsigned int x3 = xu[(size_t)e23.z * 64 + lane];
        unsigned int r3 = ru[(size_t)e23.w * 64 + lane];
        ax += (bf2f(x0 & 0xffffu) + bf2f(r0 & 0xffffu))
            + (bf2f(x1 & 0xffffu) + bf2f(r1 & 0xffffu))
            + (bf2f(x2 & 0xffffu) + bf2f(r2 & 0xffffu))
            + (bf2f(x3 & 0xffffu) + bf2f(r3 & 0xffffu));
        ay += (bf2f(x0 >> 16) + bf2f(r0 >> 16))
            + (bf2f(x1 >> 16) + bf2f(r1 >> 16))
            + (bf2f(x2 >> 16) + bf2f(r2 >> 16))
            + (bf2f(x3 >> 16) + bf2f(r3 >> 16));
    }
    if (j + 2 <= cc) {
        int4 e01 = *(const int4*)(sl + j);
        unsigned int x0 = xu[(size_t)e01.x * 64 + lane];
        unsigned int r0 = ru[(size_t)e01.y * 64 + lane];
        unsigned int x1 = xu[(size_t)e01.z * 64 + lane];
        unsigned int r1 = ru[(size_t)e01.w * 64 + lane];
        ax += (bf2f(x0 & 0xffffu) + bf2f(r0 & 0xffffu))
            + (bf2f(x1 & 0xffffu) + bf2f(r1 & 0xffffu));
        ay += (bf2f(x0 >> 16) + bf2f(r0 >> 16))
            + (bf2f(x1 >> 16) + bf2f(r1 >> 16));
        j += 2;
    }
    if (j < cc) {
        int2 se = sl[j];
        unsigned int xa = xu[(size_t)se.x * 64 + lane];
        unsigned int ra = ru[(size_t)se.y * 64 + lane];
        ax += bf2f(xa & 0xffffu) + bf2f(ra & 0xffffu);
        ay += bf2f(xa >> 16) + bf2f(ra >> 16);
    }
    float inv = 1.f / fmaxf((float)c, 1.f);
    unsigned int pack = (unsigned int)f2bf(ax * inv)
                      | ((unsigned int)f2bf(ay * inv) << 16);
    ((unsigned int*)tokens)[((size_t)n * 5 + w + 1) * 64 + lane] = pack;
}

// ---------------------------------------------------------------------------
// MEGA: gemm1 + scan + out fused per 16-node block (80 token rows).
// 512 threads. Scan phase k-SPLIT across lane pairs (lane, lane^32):
// each thread owns 8 of 16 state slots -> ~36 live floats (was ~58),
// single __shfl_xor(total,32) combine. Fits VGPR cap 128 with no spill
// (R6: 512thr demanded ~100 -> scratch spill, 650 MB HBM traffic, 223us).
// ---------------------------------------------------------------------------
__global__ __launch_bounds__(512, 4) void mega(
    const unsigned short* __restrict__ tokens,
    const unsigned short* __restrict__ Bp,
    const unsigned short* __restrict__ Wop,
    const unsigned short* __restrict__ Wgp,
    const unsigned short* __restrict__ x_bf,
    const float* __restrict__ x,
    const float* __restrict__ log_A,
    const float* __restrict__ b_delta, const float* __restrict__ b_g,
    const float* __restrict__ b_out,
    const float* __restrict__ ln_g, const float* __restrict__ ln_b,
    float* __restrict__ out)
{
    const int tid = threadIdx.x;
    const int wv = tid >> 6, lane = tid & 63;
    const int quad = lane >> 4, l16 = lane & 15;
    const int m0 = blockIdx.x * 80;       // global token-row base
    const int n0 = blockIdx.x * 16;       // global node base

    // LDS: phase1 {delta 20480 | bcf 10240 | so 4096}, out-phase aliases
    // res/pmu/pv2/mu into the (then-dead) delta/bcf regions.
    __shared__ __align__(16) char smem[34816];
    unsigned short* s_delta = (unsigned short*)smem;            // [80][128] bf16
    float*          s_bcf   = (float*)(smem + 20480);           // [80][32] f32
    unsigned short* s_so    = (unsigned short*)(smem + 30720);  // [16][128] bf16 (swz)
    float* s_res  = (float*)smem;                               // [16][132] f32
    float* s_pmu  = (float*)(smem + 20480);                     // [16][16]
    float* s_pv2  = (float*)(smem + 21504);                     // [16][16]
    float* s_mu   = (float*)(smem + 22528);                     // [16]
    float* s_rstd = (float*)(smem + 22592);                     // [16]

    // ---------------- phase 1: GEMM1  Z[80,160] -> s_delta | s_bcf
    // 50 units = 5 row-frags x 10 col-tiles, round-robin over 8 waves.
    for (int u = wv; u < 50; u += 8) {
        int f = u / 10, t = u - (u / 10) * 10;
        f32x4 acc = {0.f, 0.f, 0.f, 0.f};
        const unsigned short* arow =
            tokens + (size_t)(m0 + f * 16 + l16) * 128 + quad * 8;
        #pragma unroll
        for (int kc = 0; kc < 128; kc += 32) {
            bf16x8 a = *(const bf16x8*)(arow + kc);
            bf16x8 b = *(const bf16x8*)(Bp +
                ((size_t)(kc / 8 + quad) * NCOLS + 16 * t + l16) * 8);
            acc = __builtin_amdgcn_mfma_f32_16x16x32_bf16(a, b, acc, 0, 0, 0);
        }
        int rbase = f * 16 + quad * 4;
        int c = 16 * t + l16;
        #pragma unroll
        for (int reg = 0; reg < 4; ++reg) {
            int r = rbase + reg;              // local row 0..79 (= node*5+s)
            float v = acc[reg];
            if (t < 8) {
                float z = v + b_delta[c];
                float d = (z > 15.f) ? z : log1pf(__expf(z));
                s_delta[r * 128 + c] = f2bf(d);
            } else {
                s_bcf[r * 32 + (c - 128)] = v;   // f32 (B:0-15 | C:16-31)
            }
        }
    }
    __syncthreads();

    // ---------------- phase 2: bidirectional selective scan -> s_so
    // k-split: khalf = lane>>5 owns k in [8*khalf, 8*khalf+8).
    // dim = (wv&3)*32 + (lane&31)  (CONSTANT per thread -> Ac hoisted)
    // node = 2*i + (wv>>2), i = 0..7.
    {
        const int lane32 = lane & 31;
        const int khalf  = lane >> 5;
        const int dim    = ((wv & 3) << 5) | lane32;
        float Ac[8];
        {
            const float4* la = (const float4*)(log_A + dim * 16 + khalf * 8);
            #pragma unroll
            for (int q = 0; q < 2; ++q) {
                float4 lv = la[q];
                Ac[q * 4 + 0] = -__expf(lv.x);
                Ac[q * 4 + 1] = -__expf(lv.y);
                Ac[q * 4 + 2] = -__expf(lv.z);
                Ac[q * 4 + 3] = -__expf(lv.w);
            }
        }
        #pragma unroll 1          // keep phase-2 body I-cache-resident
        for (int i = 0; i < 8; ++i) {
            int node = (wv >> 2) + 2 * i;     // local node 0..15
            const float* bcn = s_bcf + node * 160 + khalf * 8;   // [5][32] + k-off
            float tv[5], dl[5];
            {
                const unsigned short* tb =
                    tokens + ((size_t)(n0 + node) * 5) * 128 + dim;
                const unsigned short* db = s_delta + node * 640 + dim;
                #pragma unroll
                for (int s = 0; s < 5; ++s) {
                    tv[s] = bf2f(tb[s * 128]);
                    dl[s] = bf2f(db[s * 128]);
                }
            }
            float st[8], V[8];
            #pragma unroll
            for (int k = 0; k < 8; ++k) { st[k] = 0.f; V[k] = bcn[16 + k]; }
            float total = 0.f;
            #pragma unroll
            for (int s = 0; s < 5; ++s) {
                float dtv = dl[s] * tv[s];
                float yf = 0.f, ub = 0.f;
                #pragma unroll
                for (int k = 0; k < 8; ++k) {
                    float B = bcn[s * 32 + k];
                    float C = bcn[s * 32 + 16 + k];
                    float A = __expf(dl[s] * Ac[k]);
                    st[k] = fmaf(A, st[k], dtv * B);
                    yf = fmaf(st[k], C, yf);
                    ub = fmaf(V[k], B, ub);              // V_s (pre-update)
                    if (s < 4) V[k] = fmaf(A, V[k], bcn[(s + 1) * 32 + 16 + k]);
                }
                total += yf + dtv * ub;
            }
            total += __shfl_xor(total, 32, 64);          // combine k-halves
            if (khalf == 0) {
                // swizzled store: chunk(16B) ^= node&7 -> conflict-free b128 reads
                s_so[node * 128 + (((dim >> 3) ^ (node & 7)) << 3) + (dim & 7)] =
                    f2bf(total * 0.2f);
            }
        }
    }
    __syncthreads();

    // ---------------- phase 3: out = LN(x + silu(x@Wg+bg)*(so@Wo+bo))
    // 8 waves: wave wv owns col-tile [16wv, 16wv+16).
    {
        f32x4 accO = {0,0,0,0};
        f32x4 accG = {0,0,0,0};
        const unsigned short* grow = x_bf + (size_t)(n0 + l16) * 128 + quad * 8;
        #pragma unroll
        for (int kc = 0; kc < 128; kc += 32) {
            // so A-frag from LDS with matching swizzle (row=l16, chunk=kc/8+quad)
            bf16x8 a = *(const bf16x8*)(s_so + l16 * 128 +
                           (((kc / 8 + quad) ^ (l16 & 7)) << 3));
            bf16x8 ag = *(const bf16x8*)(grow + kc);
            size_t bi = ((size_t)(kc / 8 + quad) * 128 + 16 * wv + l16) * 8;
            bf16x8 bo = *(const bf16x8*)(Wop + bi);
            bf16x8 bg = *(const bf16x8*)(Wgp + bi);
            accO = __builtin_amdgcn_mfma_f32_16x16x32_bf16(a,  bo, accO, 0, 0, 0);
            accG = __builtin_amdgcn_mfma_f32_16x16x32_bf16(ag, bg, accG, 0, 0, 0);
        }

        {
            int c = wv * 16 + l16;
            #pragma unroll
            for (int reg = 0; reg < 4; ++reg) {
                int lrow = quad * 4 + reg;
                float o  = accO[reg] + b_out[c];
                float gl = accG[reg] + b_g[c];
                float gate = gl / (1.f + __expf(-gl));
                s_res[lrow * 132 + c] = x[(size_t)(n0 + lrow) * 128 + c] + gate * o;
            }
        }
        __syncthreads();

        if (tid < 256) {
            int row = tid >> 4, q = tid & 15;
            float s = 0.f, s2 = 0.f;
            #pragma unroll
            for (int i = 0; i < 8; ++i) {
                float vv = s_res[row * 132 + q + 16 * i];
                s += vv; s2 += vv * vv;
            }
            s_pmu[row * 16 + q] = s; s_pv2[row * 16 + q] = s2;
        }
        __syncthreads();
        if (tid < 16) {
            float s = 0.f, s2 = 0.f;
            #pragma unroll
            for (int i = 0; i < 16; ++i) { s += s_pmu[tid * 16 + i]; s2 += s_pv2[tid * 16 + i]; }
            float mu = s * (1.f / 128.f);
            float var = s2 * (1.f / 128.f) - mu * mu;
            s_mu[tid] = mu;
            s_rstd[tid] = rsqrtf(var + LN_EPS);
        }
        __syncthreads();
        #pragma unroll
        for (int i = 0; i < 4; ++i) {
            int idx = i * 512 + tid;
            int row = idx >> 7, c = idx & 127;
            out[(size_t)(n0 + row) * 128 + c] =
                (s_res[row * 132 + c] - s_mu[row]) * s_rstd[row] * ln_g[c] + ln_b[c];
        }
    }
}

// ---------------------------------------------------------------------------
extern "C" void kernel_launch(void* const* d_in, const int* in_sizes, int n_in,
                              void* d_out, int out_size, void* d_ws, size_t ws_size,
                              hipStream_t stream) {
    const float* x          = (const float*)d_in[0];
    const int*   edge_index = (const int*)  d_in[1];
    const int*   edge_type  = (const int*)  d_in[2];
    const int*   perms      = (const int*)  d_in[3];
    const float* rel_table  = (const float*)d_in[4];
    const float* log_A      = (const float*)d_in[5];
    const float* W_B        = (const float*)d_in[6];
    const float* W_C        = (const float*)d_in[7];
    const float* W_delta    = (const float*)d_in[8];
    const float* b_delta    = (const float*)d_in[9];
    const float* W_g        = (const float*)d_in[10];
    const float* b_g        = (const float*)d_in[11];
    const float* W_out      = (const float*)d_in[12];
    const float* b_out      = (const float*)d_in[13];
    const float* ln_g       = (const float*)d_in[14];
    const float* ln_b       = (const float*)d_in[15];

    char* ws = (char*)d_ws;
    int*            cnt    = (int*)           (ws + 0);          //   163840
    unsigned short* Bp     = (unsigned short*)(ws + 163840);     //    40960
    unsigned short* Wop    = (unsigned short*)(ws + 204800);     //    32768
    unsigned short* Wgp    = (unsigned short*)(ws + 237568);     //    32768
    unsigned short* x_bf   = (unsigned short*)(ws + 270336);     //  2560000
    unsigned short* rel_bf = (unsigned short*)(ws + 2830336);    //    51200
    unsigned short* tokens = (unsigned short*)(ws + 2881536);    // 12800000
    int2*           slots  = (int2*)          (ws + 15681536);   // 10485760

    (void)hipMemsetAsync(cnt, 0, 163840, stream);   // cnt pre-zero (csr atomics)

    prep_all<<<6558, 256, 0, stream>>>(
        W_delta, W_B, W_C, W_g, W_out, x, rel_table, edge_index, edge_type,
        perms, Bp, Wop, Wgp, x_bf, rel_bf, cnt, slots, tokens);

    gather_tokens<<<N_NODES, 256, 0, stream>>>(
        x_bf, cnt, slots, rel_bf, tokens);

    mega<<<N_NODES / 16, 512, 0, stream>>>(
        tokens, Bp, Wop, Wgp, x_bf, x, log_A, b_delta, b_g, b_out,
        ln_g, ln_b, (float*)d_out);
}

// Round 8
// 195.622 us; speedup vs baseline: 1.7485x; 1.0058x over previous
//
#include <hip/hip_runtime.h>
#include <hip/hip_bf16.h>
#include <math.h>

#define N_NODES 10000
#define D_MODEL 128
#define E_EDGES 320000
#define P_EDGES 80000
#define LN_EPS 1e-5f
#define CAP 32             // slots per bucket (Poisson(8): P(>32) ~ 1e-11)
#define M_ROWS 50000       // = 625 blocks * 80 rows, exact
#define NCOLS 160          // delta(128) + B(16) + C(16)

typedef __attribute__((ext_vector_type(8))) short bf16x8;
typedef __attribute__((ext_vector_type(4))) float f32x4;

#if __has_builtin(__builtin_amdgcn_exp2f)
#define EXP2(x) __builtin_amdgcn_exp2f(x)
#else
#define EXP2(x) exp2f(x)
#endif
#define LOG2E 1.44269504088896f

__device__ __forceinline__ unsigned short f2bf(float f) {
    __hip_bfloat16 h = __float2bfloat16(f);
    return *reinterpret_cast<unsigned short*>(&h);
}
__device__ __forceinline__ float bf2f(unsigned int u) {
    return __uint_as_float(u << 16);
}

// ---------------------------------------------------------------------------
// prep_all (+csr folded in): pack Wcat(160) + W_out + W_g, x/rel -> bf16
// (x also into s=0 token rows), AND the CSR bucket scatter (cnt pre-zeroed
// by hipMemsetAsync).
// ---------------------------------------------------------------------------
__global__ __launch_bounds__(256) void prep_all(
    const float* __restrict__ Wd, const float* __restrict__ Wb,
    const float* __restrict__ Wc, const float* __restrict__ Wg,
    const float* __restrict__ W_out,
    const float* __restrict__ x, const float* __restrict__ rel,
    const int* __restrict__ edge_index, const int* __restrict__ edge_type,
    const int* __restrict__ perms,
    unsigned short* __restrict__ Bp, unsigned short* __restrict__ Wop,
    unsigned short* __restrict__ Wgp,
    unsigned short* __restrict__ x_bf, unsigned short* __restrict__ rel_bf,
    int* __restrict__ cnt, int2* __restrict__ slots,
    unsigned short* __restrict__ tokens)
{
    int gid = blockIdx.x * 256 + threadIdx.x;
    if (gid < 20480) {                         // Bp: 128 x 160
        int k = gid / NCOLS, n = gid - (gid / NCOLS) * NCOLS;
        float v;
        if (n < 128)      v = Wd[k * 128 + n];
        else if (n < 144) v = Wb[k * 16 + (n - 128)];
        else              v = Wc[k * 16 + (n - 144)];
        Bp[((size_t)(k >> 3) * NCOLS + n) * 8 + (k & 7)] = f2bf(v);
    } else if (gid < 36864) {                  // Wop: 128 x 128
        int i = gid - 20480;
        int k = i >> 7, n = i & 127;
        Wop[((size_t)(k >> 3) * 128 + n) * 8 + (k & 7)] = f2bf(W_out[k * 128 + n]);
    } else if (gid < 53248) {                  // Wgp: 128 x 128
        int i = gid - 36864;
        int k = i >> 7, n = i & 127;
        Wgp[((size_t)(k >> 3) * 128 + n) * 8 + (k & 7)] = f2bf(Wg[k * 128 + n]);
    } else if (gid < 78848) {                  // rel_bf
        int i = gid - 53248;
        rel_bf[i] = f2bf(rel[i]);
    } else if (gid < 1358848) {                // x -> bf16 + s=0 token rows
        int i = gid - 78848;
        unsigned short v = f2bf(x[i]);
        x_bf[i] = v;
        tokens[(size_t)(i >> 7) * 640 + (i & 127)] = v;
    } else if (gid < 1678848) {                // CSR scatter (cnt pre-zeroed)
        int i = gid - 1358848;
        int s = i / P_EDGES;
        int e = perms[i];
        int src = edge_index[e];
        int dst = edge_index[E_EDGES + e];
        int ty  = edge_type[e];
        int b = dst * 4 + s;
        int pos = atomicAdd(&cnt[b], 1);
        if (pos < CAP) slots[(size_t)b * CAP + pos] = make_int2(src, ty);
    }
}

// ---------------------------------------------------------------------------
// Gather (wide: 10000 blocks): one wave per bucket; lane = 2 dims;
// 4 edges in flight.
// ---------------------------------------------------------------------------
__global__ __launch_bounds__(256) void gather_tokens(
    const unsigned short* __restrict__ x_bf,
    const int* __restrict__ cnt, const int2* __restrict__ slots,
    const unsigned short* __restrict__ rel_bf,
    unsigned short* __restrict__ tokens)
{
    int n = blockIdx.x;
    int w = threadIdx.x >> 6, lane = threadIdx.x & 63;
    int b = n * 4 + w;
    int c = cnt[b];
    int cc = c < CAP ? c : CAP;
    const int2* sl = slots + (size_t)b * CAP;
    const unsigned int* xu = (const unsigned int*)x_bf;
    const unsigned int* ru = (const unsigned int*)rel_bf;
    float ax = 0.f, ay = 0.f;
    int j = 0;
    for (; j + 4 <= cc; j += 4) {
        int4 e01 = *(const int4*)(sl + j);
        int4 e23 = *(const int4*)(sl + j + 2);
        unsigned int x0 = xu[(size_t)e01.x * 64 + lane];
        unsigned int r0 = ru[(size_t)e01.y * 64 + lane];
        unsigned int x1 = xu[(size_t)e01.z * 64 + lane];
        unsigned int r1 = ru[(size_t)e01.w * 64 + lane];
        unsigned int x2 = xu[(size_t)e23.x * 64 + lane];
        unsigned int r2 = ru[(size_t)e23.y * 64 + lane];
        unsigned int x3 = xu[(size_t)e23.z * 64 + lane];
        unsigned int r3 = ru[(size_t)e23.w * 64 + lane];
        ax += (bf2f(x0 & 0xffffu) + bf2f(r0 & 0xffffu))
            + (bf2f(x1 & 0xffffu) + bf2f(r1 & 0xffffu))
            + (bf2f(x2 & 0xffffu) + bf2f(r2 & 0xffffu))
            + (bf2f(x3 & 0xffffu) + bf2f(r3 & 0xffffu));
        ay += (bf2f(x0 >> 16) + bf2f(r0 >> 16))
            + (bf2f(x1 >> 16) + bf2f(r1 >> 16))
            + (bf2f(x2 >> 16) + bf2f(r2 >> 16))
            + (bf2f(x3 >> 16) + bf2f(r3 >> 16));
    }
    if (j + 2 <= cc) {
        int4 e01 = *(const int4*)(sl + j);
        unsigned int x0 = xu[(size_t)e01.x * 64 + lane];
        unsigned int r0 = ru[(size_t)e01.y * 64 + lane];
        unsigned int x1 = xu[(size_t)e01.z * 64 + lane];
        unsigned int r1 = ru[(size_t)e01.w * 64 + lane];
        ax += (bf2f(x0 & 0xffffu) + bf2f(r0 & 0xffffu))
            + (bf2f(x1 & 0xffffu) + bf2f(r1 & 0xffffu));
        ay += (bf2f(x0 >> 16) + bf2f(r0 >> 16))
            + (bf2f(x1 >> 16) + bf2f(r1 >> 16));
        j += 2;
    }
    if (j < cc) {
        int2 se = sl[j];
        unsigned int xa = xu[(size_t)se.x * 64 + lane];
        unsigned int ra = ru[(size_t)se.y * 64 + lane];
        ax += bf2f(xa & 0xffffu) + bf2f(ra & 0xffffu);
        ay += bf2f(xa >> 16) + bf2f(ra >> 16);
    }
    float inv = 1.f / fmaxf((float)c, 1.f);
    unsigned int pack = (unsigned int)f2bf(ax * inv)
                      | ((unsigned int)f2bf(ay * inv) << 16);
    ((unsigned int*)tokens)[((size_t)n * 5 + w + 1) * 64 + lane] = pack;
}

// ---------------------------------------------------------------------------
// MEGA: gemm1 + scan + out fused per 16-node block. 512 threads, k-split scan.
// R7 rework: scan inner loop de-scalarized -- B/C via ds_read_b128 (float4
// pairs), V-update deferred (W=A*V held across s, V=W+C on fresh C), delta
// stored TRANSPOSED [node][dim][8] so dl is one b128 read, exp2-folded Ac.
// LDS instr per node-iter: ~120 b32 -> ~21 wide reads (was the 67%-VALUBusy
// issue bottleneck at 74us).
// ---------------------------------------------------------------------------
__global__ __launch_bounds__(512, 4) void mega(
    const unsigned short* __restrict__ tokens,
    const unsigned short* __restrict__ Bp,
    const unsigned short* __restrict__ Wop,
    const unsigned short* __restrict__ Wgp,
    const unsigned short* __restrict__ x_bf,
    const float* __restrict__ x,
    const float* __restrict__ log_A,
    const float* __restrict__ b_delta, const float* __restrict__ b_g,
    const float* __restrict__ b_out,
    const float* __restrict__ ln_g, const float* __restrict__ ln_b,
    float* __restrict__ out)
{
    const int tid = threadIdx.x;
    const int wv = tid >> 6, lane = tid & 63;
    const int quad = lane >> 4, l16 = lane & 15;
    const int m0 = blockIdx.x * 80;       // global token-row base
    const int n0 = blockIdx.x * 16;       // global node base

    // LDS phase1/2: deltaT 32768 | bcf 10240 | so 4096  (47104 B total)
    // phase3 aliases res/pmu/pv2/mu into the then-dead deltaT region.
    __shared__ __align__(16) char smem[47104];
    unsigned short* s_deltaT = (unsigned short*)smem;           // [16][128][8]
    float*          s_bcf    = (float*)(smem + 32768);          // [80][32] f32
    unsigned short* s_so     = (unsigned short*)(smem + 43008); // [16][128] bf16 swz
    float* s_res  = (float*)smem;                               // [16][132] f32
    float* s_pmu  = (float*)(smem + 8448);                      // [16][16]
    float* s_pv2  = (float*)(smem + 9472);                      // [16][16]
    float* s_mu   = (float*)(smem + 10496);                     // [16]
    float* s_rstd = (float*)(smem + 10560);                     // [16]

    // ---------------- phase 1: GEMM1  Z[80,160] -> s_deltaT | s_bcf
    for (int u = wv; u < 50; u += 8) {
        int f = u / 10, t = u - (u / 10) * 10;
        f32x4 acc = {0.f, 0.f, 0.f, 0.f};
        const unsigned short* arow =
            tokens + (size_t)(m0 + f * 16 + l16) * 128 + quad * 8;
        #pragma unroll
        for (int kc = 0; kc < 128; kc += 32) {
            bf16x8 a = *(const bf16x8*)(arow + kc);
            bf16x8 b = *(const bf16x8*)(Bp +
                ((size_t)(kc / 8 + quad) * NCOLS + 16 * t + l16) * 8);
            acc = __builtin_amdgcn_mfma_f32_16x16x32_bf16(a, b, acc, 0, 0, 0);
        }
        int rbase = f * 16 + quad * 4;
        int c = 16 * t + l16;
        #pragma unroll
        for (int reg = 0; reg < 4; ++reg) {
            int r = rbase + reg;              // local row 0..79 (= node*5+s)
            float v = acc[reg];
            if (t < 8) {
                float z = v + b_delta[c];
                float d = (z > 15.f) ? z : log1pf(__expf(z));
                int nd = r / 5, sx = r - nd * 5;
                s_deltaT[nd * 1024 + c * 8 + sx] = f2bf(d);   // transposed
            } else {
                s_bcf[r * 32 + (c - 128)] = v;   // f32 (B:0-15 | C:16-31)
            }
        }
    }
    __syncthreads();

    // ---------------- phase 2: bidirectional selective scan -> s_so
    // k-split: khalf = lane>>5 owns 8 of 16 k-slots; combine via shfl_xor.
    {
        const int lane32 = lane & 31;
        const int khalf  = lane >> 5;
        const int dim    = ((wv & 3) << 5) | lane32;
        float Ac[8];
        {
            const float4* la = (const float4*)(log_A + dim * 16 + khalf * 8);
            float4 lv0 = la[0], lv1 = la[1];
            Ac[0] = -__expf(lv0.x) * LOG2E;
            Ac[1] = -__expf(lv0.y) * LOG2E;
            Ac[2] = -__expf(lv0.z) * LOG2E;
            Ac[3] = -__expf(lv0.w) * LOG2E;
            Ac[4] = -__expf(lv1.x) * LOG2E;
            Ac[5] = -__expf(lv1.y) * LOG2E;
            Ac[6] = -__expf(lv1.z) * LOG2E;
            Ac[7] = -__expf(lv1.w) * LOG2E;
        }
        #pragma unroll 1          // keep body I-cache-resident
        for (int i = 0; i < 8; ++i) {
            int node = (wv >> 2) + 2 * i;     // local node 0..15
            const float* bcn = s_bcf + node * 160 + khalf * 8;
            float tv[5];
            {
                const unsigned short* tb =
                    tokens + (size_t)(n0 + node) * 640 + dim;
                #pragma unroll
                for (int s = 0; s < 5; ++s) tv[s] = bf2f(tb[s * 128]);
            }
            bf16x8 dpk = *(const bf16x8*)(s_deltaT + node * 1024 + dim * 8);
            const unsigned short* dvp = (const unsigned short*)&dpk;
            float st[8], V[8];
            #pragma unroll
            for (int k = 0; k < 8; ++k) st[k] = 0.f;
            float total = 0.f;
            #pragma unroll
            for (int s = 0; s < 5; ++s) {
                float dlS = bf2f(dvp[s]);
                float dtv = dlS * tv[s];
                f32x4 Bv0 = *(const f32x4*)(bcn + s * 32);
                f32x4 Bv1 = *(const f32x4*)(bcn + s * 32 + 4);
                f32x4 Cv0 = *(const f32x4*)(bcn + s * 32 + 16);
                f32x4 Cv1 = *(const f32x4*)(bcn + s * 32 + 20);
                float yf = 0.f, ub = 0.f;
                #pragma unroll
                for (int k = 0; k < 8; ++k) {
                    float B = (k < 4) ? Bv0[k] : Bv1[k - 4];
                    float C = (k < 4) ? Cv0[k] : Cv1[k - 4];
                    float Vs = (s == 0) ? C : V[k] + C;      // V_s
                    float A = EXP2(dlS * Ac[k]);             // exp(dl * A_cont)
                    st[k] = fmaf(A, st[k], dtv * B);
                    yf = fmaf(st[k], C, yf);
                    ub = fmaf(Vs, B, ub);                    // V_s pre-update
                    V[k] = A * Vs;                           // W for next s
                }
                total += yf + dtv * ub;
            }
            total += __shfl_xor(total, 32, 64);              // combine k-halves
            if (khalf == 0) {
                // swizzled store: chunk(16B) ^= node&7 -> conflict-free b128
                s_so[node * 128 + (((dim >> 3) ^ (node & 7)) << 3) + (dim & 7)] =
                    f2bf(total * 0.2f);
            }
        }
    }
    __syncthreads();

    // ---------------- phase 3: out = LN(x + silu(x@Wg+bg)*(so@Wo+bo))
    // 8 waves: wave wv owns col-tile [16wv, 16wv+16).
    {
        f32x4 accO = {0,0,0,0};
        f32x4 accG = {0,0,0,0};
        const unsigned short* grow = x_bf + (size_t)(n0 + l16) * 128 + quad * 8;
        #pragma unroll
        for (int kc = 0; kc < 128; kc += 32) {
            bf16x8 a = *(const bf16x8*)(s_so + l16 * 128 +
                           (((kc / 8 + quad) ^ (l16 & 7)) << 3));
            bf16x8 ag = *(const bf16x8*)(grow + kc);
            size_t bi = ((size_t)(kc / 8 + quad) * 128 + 16 * wv + l16) * 8;
            bf16x8 bo = *(const bf16x8*)(Wop + bi);
            bf16x8 bg = *(const bf16x8*)(Wgp + bi);
            accO = __builtin_amdgcn_mfma_f32_16x16x32_bf16(a,  bo, accO, 0, 0, 0);
            accG = __builtin_amdgcn_mfma_f32_16x16x32_bf16(ag, bg, accG, 0, 0, 0);
        }

        {
            int c = wv * 16 + l16;
            #pragma unroll
            for (int reg = 0; reg < 4; ++reg) {
                int lrow = quad * 4 + reg;
                float o  = accO[reg] + b_out[c];
                float gl = accG[reg] + b_g[c];
                float gate = gl / (1.f + __expf(-gl));
                s_res[lrow * 132 + c] = x[(size_t)(n0 + lrow) * 128 + c] + gate * o;
            }
        }
        __syncthreads();

        if (tid < 256) {
            int row = tid >> 4, q = tid & 15;
            float s = 0.f, s2 = 0.f;
            #pragma unroll
            for (int i = 0; i < 8; ++i) {
                float vv = s_res[row * 132 + q + 16 * i];
                s += vv; s2 += vv * vv;
            }
            s_pmu[row * 16 + q] = s; s_pv2[row * 16 + q] = s2;
        }
        __syncthreads();
        if (tid < 16) {
            float s = 0.f, s2 = 0.f;
            #pragma unroll
            for (int i = 0; i < 16; ++i) { s += s_pmu[tid * 16 + i]; s2 += s_pv2[tid * 16 + i]; }
            float mu = s * (1.f / 128.f);
            float var = s2 * (1.f / 128.f) - mu * mu;
            s_mu[tid] = mu;
            s_rstd[tid] = rsqrtf(var + LN_EPS);
        }
        __syncthreads();
        #pragma unroll
        for (int i = 0; i < 4; ++i) {
            int idx = i * 512 + tid;
            int row = idx >> 7, c = idx & 127;
            out[(size_t)(n0 + row) * 128 + c] =
                (s_res[row * 132 + c] - s_mu[row]) * s_rstd[row] * ln_g[c] + ln_b[c];
        }
    }
}

// ---------------------------------------------------------------------------
extern "C" void kernel_launch(void* const* d_in, const int* in_sizes, int n_in,
                              void* d_out, int out_size, void* d_ws, size_t ws_size,
                              hipStream_t stream) {
    const float* x          = (const float*)d_in[0];
    const int*   edge_index = (const int*)  d_in[1];
    const int*   edge_type  = (const int*)  d_in[2];
    const int*   perms      = (const int*)  d_in[3];
    const float* rel_table  = (const float*)d_in[4];
    const float* log_A      = (const float*)d_in[5];
    const float* W_B        = (const float*)d_in[6];
    const float* W_C        = (const float*)d_in[7];
    const float* W_delta    = (const float*)d_in[8];
    const float* b_delta    = (const float*)d_in[9];
    const float* W_g        = (const float*)d_in[10];
    const float* b_g        = (const float*)d_in[11];
    const float* W_out      = (const float*)d_in[12];
    const float* b_out      = (const float*)d_in[13];
    const float* ln_g       = (const float*)d_in[14];
    const float* ln_b       = (const float*)d_in[15];

    char* ws = (char*)d_ws;
    int*            cnt    = (int*)           (ws + 0);          //   163840
    unsigned short* Bp     = (unsigned short*)(ws + 163840);     //    40960
    unsigned short* Wop    = (unsigned short*)(ws + 204800);     //    32768
    unsigned short* Wgp    = (unsigned short*)(ws + 237568);     //    32768
    unsigned short* x_bf   = (unsigned short*)(ws + 270336);     //  2560000
    unsigned short* rel_bf = (unsigned short*)(ws + 2830336);    //    51200
    unsigned short* tokens = (unsigned short*)(ws + 2881536);    // 12800000
    int2*           slots  = (int2*)          (ws + 15681536);   // 10485760

    (void)hipMemsetAsync(cnt, 0, 163840, stream);   // cnt pre-zero (csr atomics)

    prep_all<<<6558, 256, 0, stream>>>(
        W_delta, W_B, W_C, W_g, W_out, x, rel_table, edge_index, edge_type,
        perms, Bp, Wop, Wgp, x_bf, rel_bf, cnt, slots, tokens);

    gather_tokens<<<N_NODES, 256, 0, stream>>>(
        x_bf, cnt, slots, rel_bf, tokens);

    mega<<<N_NODES / 16, 512, 0, stream>>>(
        tokens, Bp, Wop, Wgp, x_bf, x, log_A, b_delta, b_g, b_out,
        ln_g, ln_b, (float*)d_out);
}